// Round 2
// baseline (52.944 us; speedup 1.0000x reference)
//
#include <hip/hip_runtime.h>
#include <hip/hip_bf16.h>

#define BS  32
#define J   4
#define L   512
#define D   768
#define K   4
#define OUT 256
// entity index e = b*16 + j*4 + k  (matches reference reshape order), e in [0,512)

// ---------------- Kernel A: ragged span mean-pool ----------------
// grid = 512 (one block per entity), block = 512 threads (2 token sub-groups x 256)
__global__ __launch_bounds__(512) void pool_kernel(
    const float* __restrict__ Z,    // [BS, J, L, D]
    const int*   __restrict__ sep,  // [BS, J, K]
    float*       __restrict__ pooled) // [512, D] workspace
{
    const int e   = blockIdx.x;
    const int b   = e >> 4;
    const int j   = (e >> 2) & 3;
    const int k   = e & 3;
    const int sub = threadIdx.x >> 8;   // 0..1: token sub-group
    const int t   = threadIdx.x & 255;  // dim lane: owns dims t, t+256, t+512

    const int sbase = (b * J + j) * K;
    const int end   = sep[sbase + k];
    const int start = (k == 0) ? 1 : (sep[sbase + k - 1] + 1);
    const float inv = 1.0f / (float)(end - start);

    const float* zrow = Z + ((size_t)(b * J + j) * L) * D;

    float a0 = 0.f, a1 = 0.f, a2 = 0.f;
    for (int l = start + sub; l < end; l += 2) {
        const float* r = zrow + (size_t)l * D;
        a0 += r[t];
        a1 += r[t + 256];
        a2 += r[t + 512];
    }

    __shared__ float part[2][D];
    part[sub][t]       = a0;
    part[sub][t + 256] = a1;
    part[sub][t + 512] = a2;
    __syncthreads();

    if (threadIdx.x < 256) {
        float s0 = (part[0][t]       + part[1][t])       * inv;
        float s1 = (part[0][t + 256] + part[1][t + 256]) * inv;
        float s2 = (part[0][t + 512] + part[1][t + 512]) * inv;
        float* dst = pooled + (size_t)e * D;
        dst[t]       = s0;
        dst[t + 256] = s1;
        dst[t + 512] = s2;
    }
}

// ---------------- Kernel B: [512,768] @ [768,256] + b ----------------
// grid = 128 entity-groups x 4 col-groups = 512 blocks, block = 256 threads.
// Wave w of a block = entity 4g+w; lane c = output col cg*64+c.
// All 4 waves read the SAME 64 W columns per d -> W fetched once/block (L1 reuse).
__global__ __launch_bounds__(256) void linear_kernel(
    const float* __restrict__ pooled, // [512, D]
    const float* __restrict__ W,      // [D, OUT]
    const float* __restrict__ bias,   // [OUT]
    float*       __restrict__ out)    // [512, OUT]
{
    const int g   = blockIdx.x >> 2;   // entity group 0..127
    const int cg  = blockIdx.x & 3;    // col group 0..3
    const int w   = threadIdx.x >> 6;  // entity within group (= wave id)
    const int c   = threadIdx.x & 63;
    const int col = cg * 64 + c;

    __shared__ float p[4 * D];         // 12 KB: the 4 pooled rows
    const float* src = pooled + (size_t)g * 4 * D;
    for (int i = threadIdx.x; i < 4 * D; i += 256) p[i] = src[i];
    __syncthreads();

    float o = bias[col];
    const float* wp = W + col;
    const float* pe = p + w * D;
    #pragma unroll 8
    for (int d = 0; d < D; ++d) {
        o += pe[d] * wp[(size_t)d * OUT];  // LDS broadcast * L1-reused W load
    }
    out[(size_t)(g * 4 + w) * OUT + col] = o;
}

extern "C" void kernel_launch(void* const* d_in, const int* in_sizes, int n_in,
                              void* d_out, int out_size, void* d_ws, size_t ws_size,
                              hipStream_t stream) {
    const float* Z    = (const float*)d_in[0];
    const int*   sep  = (const int*)d_in[1];
    const float* W    = (const float*)d_in[2];
    const float* bias = (const float*)d_in[3];
    float*       out  = (float*)d_out;
    float*       pooled = (float*)d_ws;   // 512*768*4 = 1.5 MB scratch

    pool_kernel<<<BS * J * K, 512, 0, stream>>>(Z, sep, pooled);
    linear_kernel<<<BS * J * K, 256, 0, stream>>>(pooled, W, bias, out);
}